// Round 5
// baseline (651.131 us; speedup 1.0000x reference)
//
#include <hip/hip_runtime.h>
#include <hip/hip_fp16.h>
#include <hip/hip_cooperative_groups.h>

namespace cg = cooperative_groups;

namespace {

constexpr int V_ = 256, K_ = 32, C_ = 256;
constexpr int N_ = V_ * K_;            // 8192 nodes per layer
constexpr int E_ = 32768, PF_ = 4, SF_ = 16, L_ = 5;
constexpr int B_ = 512;                // batch
constexpr int NCH = 64;                // root partial chunks
constexpr int THREADS = 256;
constexpr int MAXBLOCKS = 1024;

__device__ __forceinline__ float2 h2f(uint32_t u) {
    __half2 h = *reinterpret_cast<__half2*>(&u);
    return __half22float2(h);
}
__device__ __forceinline__ uint32_t f2h(float a, float b) {
    __half2 h = __floats2half2_rn(a, b);
    return *reinterpret_cast<uint32_t*>(&h);
}

} // namespace

// ---------------- cooperative mega-kernel (grid-stride everywhere) ----------------
__global__ __launch_bounds__(THREADS, 2) void circuit_k(
    const int* __restrict__ inp, const float* __restrict__ lp,
    const int* __restrict__ pc, const int* __restrict__ sc,
    const float* __restrict__ lw, const float* __restrict__ rw,
    float* __restrict__ out,
    uint32_t* __restrict__ nm, uint32_t* __restrict__ em,
    float* __restrict__ pm, float* __restrict__ ps)
{
    cg::grid_group grid = cg::this_grid();
    const int T = gridDim.x * blockDim.x;
    const int tid = blockIdx.x * blockDim.x + threadIdx.x;

    // ---- input layer ----
    for (int t = tid; t < V_ * K_ * (B_ / 8); t += T) {
        const int b = (t & 63) << 3;
        const int vk = t >> 6;
        const int v = vk >> 5;
        const float* row = lp + (size_t)vk * C_;
        uint4 r;
        r.x = f2h(row[inp[(b + 0) * V_ + v]], row[inp[(b + 1) * V_ + v]]);
        r.y = f2h(row[inp[(b + 2) * V_ + v]], row[inp[(b + 3) * V_ + v]]);
        r.z = f2h(row[inp[(b + 4) * V_ + v]], row[inp[(b + 5) * V_ + v]]);
        r.w = f2h(row[inp[(b + 6) * V_ + v]], row[inp[(b + 7) * V_ + v]]);
        *reinterpret_cast<uint4*>(nm + ((size_t)vk * B_ + b) / 2) = r;
    }
    grid.sync();

    for (int l = 0; l < L_; ++l) {
        const int*   pcl = pc + (size_t)l * E_ * PF_;
        const int*   scl = sc + (size_t)l * N_ * SF_;
        const float* lwl = lw + (size_t)l * N_ * SF_;

        // ---- product ----
        for (int t = tid; t < E_ * (B_ / 8); t += T) {
            const int e = t >> 6;
            const int b = (t & 63) << 3;
            const int4 ch = *reinterpret_cast<const int4*>(pcl + (size_t)e * 4);
            const uint4 u0 = *reinterpret_cast<const uint4*>(nm + ((size_t)ch.x * B_ + b) / 2);
            const uint4 u1 = *reinterpret_cast<const uint4*>(nm + ((size_t)ch.y * B_ + b) / 2);
            const uint4 u2 = *reinterpret_cast<const uint4*>(nm + ((size_t)ch.z * B_ + b) / 2);
            const uint4 u3 = *reinterpret_cast<const uint4*>(nm + ((size_t)ch.w * B_ + b) / 2);
            uint4 r;
            {
                const float2 a0 = h2f(u0.x), a1 = h2f(u1.x), a2 = h2f(u2.x), a3 = h2f(u3.x);
                r.x = f2h((a0.x + a1.x) + (a2.x + a3.x), (a0.y + a1.y) + (a2.y + a3.y));
            }
            {
                const float2 a0 = h2f(u0.y), a1 = h2f(u1.y), a2 = h2f(u2.y), a3 = h2f(u3.y);
                r.y = f2h((a0.x + a1.x) + (a2.x + a3.x), (a0.y + a1.y) + (a2.y + a3.y));
            }
            {
                const float2 a0 = h2f(u0.z), a1 = h2f(u1.z), a2 = h2f(u2.z), a3 = h2f(u3.z);
                r.z = f2h((a0.x + a1.x) + (a2.x + a3.x), (a0.y + a1.y) + (a2.y + a3.y));
            }
            {
                const float2 a0 = h2f(u0.w), a1 = h2f(u1.w), a2 = h2f(u2.w), a3 = h2f(u3.w);
                r.w = f2h((a0.x + a1.x) + (a2.x + a3.x), (a0.y + a1.y) + (a2.y + a3.y));
            }
            *reinterpret_cast<uint4*>(em + ((size_t)e * B_ + b) / 2) = r;
        }
        grid.sync();

        // ---- sum (LSE over 16 children) ----
        for (int t = tid; t < N_ * (B_ / 8); t += T) {
            const int n = t >> 6;
            const int b = (t & 63) << 3;
            int4 scv[4];
            float4 lwv[4];
            #pragma unroll
            for (int q = 0; q < 4; ++q) {
                scv[q] = *reinterpret_cast<const int4*>(scl + (size_t)n * SF_ + q * 4);
                lwv[q] = *reinterpret_cast<const float4*>(lwl + (size_t)n * SF_ + q * 4);
            }
            const int* sci = reinterpret_cast<const int*>(scv);
            const float* lwf = reinterpret_cast<const float*>(lwv);

            uint4 xr[SF_];
            #pragma unroll
            for (int s = 0; s < SF_; ++s)
                xr[s] = *reinterpret_cast<const uint4*>(em + ((size_t)sci[s] * B_ + b) / 2);

            float m[8];
            #pragma unroll
            for (int j = 0; j < 8; ++j) m[j] = -3.0e38f;
            #pragma unroll
            for (int s = 0; s < SF_; ++s) {
                const float w = lwf[s];
                const float2 f0 = h2f(xr[s].x), f1 = h2f(xr[s].y);
                const float2 f2 = h2f(xr[s].z), f3 = h2f(xr[s].w);
                m[0] = fmaxf(m[0], f0.x + w); m[1] = fmaxf(m[1], f0.y + w);
                m[2] = fmaxf(m[2], f1.x + w); m[3] = fmaxf(m[3], f1.y + w);
                m[4] = fmaxf(m[4], f2.x + w); m[5] = fmaxf(m[5], f2.y + w);
                m[6] = fmaxf(m[6], f3.x + w); m[7] = fmaxf(m[7], f3.y + w);
            }
            float acc[8];
            #pragma unroll
            for (int j = 0; j < 8; ++j) acc[j] = 0.f;
            #pragma unroll
            for (int s = 0; s < SF_; ++s) {
                const float w = lwf[s];
                const float2 f0 = h2f(xr[s].x), f1 = h2f(xr[s].y);
                const float2 f2 = h2f(xr[s].z), f3 = h2f(xr[s].w);
                acc[0] += __expf(f0.x + w - m[0]); acc[1] += __expf(f0.y + w - m[1]);
                acc[2] += __expf(f1.x + w - m[2]); acc[3] += __expf(f1.y + w - m[3]);
                acc[4] += __expf(f2.x + w - m[4]); acc[5] += __expf(f2.y + w - m[5]);
                acc[6] += __expf(f3.x + w - m[6]); acc[7] += __expf(f3.y + w - m[7]);
            }
            uint4 r;
            r.x = f2h(m[0] + __logf(acc[0]), m[1] + __logf(acc[1]));
            r.y = f2h(m[2] + __logf(acc[2]), m[3] + __logf(acc[3]));
            r.z = f2h(m[4] + __logf(acc[4]), m[5] + __logf(acc[5]));
            r.w = f2h(m[6] + __logf(acc[6]), m[7] + __logf(acc[7]));
            *reinterpret_cast<uint4*>(nm + ((size_t)n * B_ + b) / 2) = r;
        }
        grid.sync();
    }

    // ---- root stage 1 ----
    const __half* nmh = reinterpret_cast<const __half*>(nm);
    for (int t = tid; t < NCH * B_; t += T) {
        const int ch = t >> 9;
        const int b = t & (B_ - 1);
        const int n0 = ch * (N_ / NCH);
        float m = -3.0e38f, s = 0.f;
        for (int i = 0; i < N_ / NCH; ++i) {
            const int n = n0 + i;
            const float x = __half2float(nmh[(size_t)n * B_ + b]) + rw[n];
            const float mn = fmaxf(m, x);
            s = s * __expf(m - mn) + __expf(x - mn);
            m = mn;
        }
        pm[ch * B_ + b] = m;
        ps[ch * B_ + b] = s;
    }
    grid.sync();

    // ---- root stage 2 ----
    for (int t = tid; t < B_; t += T) {
        float m = -3.0e38f;
        for (int ch = 0; ch < NCH; ++ch) m = fmaxf(m, pm[ch * B_ + t]);
        float s = 0.f;
        for (int ch = 0; ch < NCH; ++ch) s += ps[ch * B_ + t] * __expf(pm[ch * B_ + t] - m);
        out[t] = m + __logf(s);
    }
}

// ---------------- fallback multi-kernel path (proven round-3 code) ----------------
namespace {

__global__ void input_layer_k(const int* __restrict__ inp, const float* __restrict__ lp,
                              uint32_t* __restrict__ nm)
{
    const int t = blockIdx.x * blockDim.x + threadIdx.x;
    const int b = (t & 127) << 2;
    const int vk = t >> 7;
    const int v = vk >> 5;
    const float* row = lp + (size_t)vk * C_;
    uint2 r;
    r.x = f2h(row[inp[(b + 0) * V_ + v]], row[inp[(b + 1) * V_ + v]]);
    r.y = f2h(row[inp[(b + 2) * V_ + v]], row[inp[(b + 3) * V_ + v]]);
    *reinterpret_cast<uint2*>(nm + ((size_t)vk * B_ + b) / 2) = r;
}

__global__ void prod_k(const uint32_t* __restrict__ nm, const int* __restrict__ pc,
                       uint32_t* __restrict__ em)
{
    const int t = blockIdx.x * blockDim.x + threadIdx.x;
    const int e = t >> 7;
    const int b = (t & 127) << 2;
    const int4 ch = *reinterpret_cast<const int4*>(pc + (size_t)e * 4);
    const uint2 u0 = *reinterpret_cast<const uint2*>(nm + ((size_t)ch.x * B_ + b) / 2);
    const uint2 u1 = *reinterpret_cast<const uint2*>(nm + ((size_t)ch.y * B_ + b) / 2);
    const uint2 u2 = *reinterpret_cast<const uint2*>(nm + ((size_t)ch.z * B_ + b) / 2);
    const uint2 u3 = *reinterpret_cast<const uint2*>(nm + ((size_t)ch.w * B_ + b) / 2);
    const float2 a0 = h2f(u0.x), b0 = h2f(u0.y);
    const float2 a1 = h2f(u1.x), b1 = h2f(u1.y);
    const float2 a2 = h2f(u2.x), b2 = h2f(u2.y);
    const float2 a3 = h2f(u3.x), b3 = h2f(u3.y);
    uint2 r;
    r.x = f2h((a0.x + a1.x) + (a2.x + a3.x), (a0.y + a1.y) + (a2.y + a3.y));
    r.y = f2h((b0.x + b1.x) + (b2.x + b3.x), (b0.y + b1.y) + (b2.y + b3.y));
    *reinterpret_cast<uint2*>(em + ((size_t)e * B_ + b) / 2) = r;
}

__global__ void sum_k(const uint32_t* __restrict__ em, const int* __restrict__ sc,
                      const float* __restrict__ lw, uint32_t* __restrict__ nm)
{
    const int t = blockIdx.x * blockDim.x + threadIdx.x;
    const int n = t >> 7;
    const int b = (t & 127) << 2;
    int4 scv[4];
    float4 lwv[4];
    #pragma unroll
    for (int q = 0; q < 4; ++q) {
        scv[q] = *reinterpret_cast<const int4*>(sc + (size_t)n * SF_ + q * 4);
        lwv[q] = *reinterpret_cast<const float4*>(lw + (size_t)n * SF_ + q * 4);
    }
    const int* sci = reinterpret_cast<const int*>(scv);
    const float* lwf = reinterpret_cast<const float*>(lwv);
    uint2 xr[SF_];
    #pragma unroll
    for (int s = 0; s < SF_; ++s)
        xr[s] = *reinterpret_cast<const uint2*>(em + ((size_t)sci[s] * B_ + b) / 2);
    float4 m = make_float4(-3.0e38f, -3.0e38f, -3.0e38f, -3.0e38f);
    #pragma unroll
    for (int s = 0; s < SF_; ++s) {
        const float w = lwf[s];
        const float2 lo = h2f(xr[s].x), hi = h2f(xr[s].y);
        m.x = fmaxf(m.x, lo.x + w);
        m.y = fmaxf(m.y, lo.y + w);
        m.z = fmaxf(m.z, hi.x + w);
        m.w = fmaxf(m.w, hi.y + w);
    }
    float4 acc = make_float4(0.f, 0.f, 0.f, 0.f);
    #pragma unroll
    for (int s = 0; s < SF_; ++s) {
        const float w = lwf[s];
        const float2 lo = h2f(xr[s].x), hi = h2f(xr[s].y);
        acc.x += __expf(lo.x + w - m.x);
        acc.y += __expf(lo.y + w - m.y);
        acc.z += __expf(hi.x + w - m.z);
        acc.w += __expf(hi.y + w - m.w);
    }
    uint2 r;
    r.x = f2h(m.x + __logf(acc.x), m.y + __logf(acc.y));
    r.y = f2h(m.z + __logf(acc.z), m.w + __logf(acc.w));
    *reinterpret_cast<uint2*>(nm + ((size_t)n * B_ + b) / 2) = r;
}

__global__ void root_part_k(const __half* __restrict__ nm, const float* __restrict__ rw,
                            float* __restrict__ pm, float* __restrict__ ps)
{
    const int b = blockIdx.x * blockDim.x + threadIdx.x;
    const int ch = blockIdx.y;
    const int n0 = ch * (N_ / NCH);
    float m = -3.0e38f, s = 0.f;
    for (int i = 0; i < N_ / NCH; ++i) {
        const int n = n0 + i;
        const float x = __half2float(nm[(size_t)n * B_ + b]) + rw[n];
        const float mn = fmaxf(m, x);
        s = s * __expf(m - mn) + __expf(x - mn);
        m = mn;
    }
    pm[ch * B_ + b] = m;
    ps[ch * B_ + b] = s;
}

__global__ void root_comb_k(const float* __restrict__ pm, const float* __restrict__ ps,
                            float* __restrict__ out)
{
    const int b = blockIdx.x * blockDim.x + threadIdx.x;
    float m = -3.0e38f;
    for (int ch = 0; ch < NCH; ++ch) m = fmaxf(m, pm[ch * B_ + b]);
    float s = 0.f;
    for (int ch = 0; ch < NCH; ++ch) s += ps[ch * B_ + b] * __expf(pm[ch * B_ + b] - m);
    out[b] = m + __logf(s);
}

} // namespace

extern "C" void kernel_launch(void* const* d_in, const int* in_sizes, int n_in,
                              void* d_out, int out_size, void* d_ws, size_t ws_size,
                              hipStream_t stream) {
    const int*   inp = (const int*)d_in[0];
    const float* lp  = (const float*)d_in[1];
    const int*   pc  = (const int*)d_in[2];
    const int*   sc  = (const int*)d_in[3];
    const float* lw  = (const float*)d_in[4];
    const float* rw  = (const float*)d_in[5];
    float*       out = (float*)d_out;

    uint32_t* nm = (uint32_t*)d_ws;                      // 8 MB (f16)
    uint32_t* em = nm + (size_t)N_ * B_ / 2;             // 32 MB (f16)
    float*    pm = (float*)(em + (size_t)E_ * B_ / 2);
    float*    ps = pm + (size_t)NCH * B_;

    // --- try the cooperative mega-kernel, sized to guaranteed co-residency ---
    int nCU = 0, maxPerCU = 0;
    bool coop_ok = false;
    if (hipDeviceGetAttribute(&nCU, hipDeviceAttributeMultiprocessorCount, 0) == hipSuccess &&
        hipOccupancyMaxActiveBlocksPerMultiprocessor(&maxPerCU, (const void*)circuit_k,
                                                     THREADS, 0) == hipSuccess &&
        maxPerCU > 0 && nCU > 0) {
        int blocks = maxPerCU * nCU;
        if (blocks > MAXBLOCKS) blocks = MAXBLOCKS;
        void* args[] = {(void*)&inp, (void*)&lp, (void*)&pc, (void*)&sc, (void*)&lw,
                        (void*)&rw, (void*)&out, (void*)&nm, (void*)&em, (void*)&pm, (void*)&ps};
        coop_ok = (hipLaunchCooperativeKernel((const void*)circuit_k, dim3(blocks),
                                              dim3(THREADS), args, 0, stream) == hipSuccess);
    }
    if (coop_ok) return;

    // --- fallback: proven multi-kernel path ---
    input_layer_k<<<(V_ * K_ * (B_ / 4)) / 256, 256, 0, stream>>>(inp, lp, nm);
    for (int l = 0; l < L_; ++l) {
        prod_k<<<(E_ * (B_ / 4)) / 256, 256, 0, stream>>>(nm, pc + (size_t)l * E_ * PF_, em);
        sum_k<<<(N_ * (B_ / 4)) / 256, 256, 0, stream>>>(
            em, sc + (size_t)l * N_ * SF_, lw + (size_t)l * N_ * SF_, nm);
    }
    root_part_k<<<dim3(B_ / 256, NCH), 256, 0, stream>>>((const __half*)nm, rw, pm, ps);
    root_comb_k<<<B_ / 256, 256, 0, stream>>>(pm, ps, out);
}

// Round 6
// 207.254 us; speedup vs baseline: 3.1417x; 3.1417x over previous
//
#include <hip/hip_runtime.h>
#include <hip/hip_fp16.h>

namespace {

constexpr int V_ = 256, K_ = 32, C_ = 256;
constexpr int N_ = V_ * K_;            // 8192 nodes per layer
constexpr int E_ = 32768, PF_ = 4, SF_ = 16, L_ = 5;
constexpr int B_ = 512;                // batch
constexpr int NCH = 64;                // root partial chunks

// batch chunking: 8 chunks of 64 -> chunk index == blockIdx & 7 == XCD id (heuristic)
constexpr int BC = 64;                 // batch elems per chunk
constexpr int LPR = BC / 8;            // lanes per row (uint4 = 8 fp16): 8

__device__ __forceinline__ float2 h2f(uint32_t u) {
    __half2 h = *reinterpret_cast<__half2*>(&u);
    return __half22float2(h);
}
__device__ __forceinline__ uint32_t f2h(float a, float b) {
    __half2 h = __floats2half2_rn(a, b);
    return *reinterpret_cast<uint32_t*>(&h);
}

// ---- input layer: nm[vk][b..b+7] = lp[vk][inputs[b..b+7][v]] ----
__global__ void input_layer_k(const int* __restrict__ inp,   // [B,V]
                              const float* __restrict__ lp,  // [V,K,C]
                              uint32_t* __restrict__ nm)     // [N,B] f16
{
    const int t = blockIdx.x * blockDim.x + threadIdx.x;  // V*K*(B/8)
    const int b = (t & 63) << 3;
    const int vk = t >> 6;
    const int v = vk >> 5;
    const float* row = lp + (size_t)vk * C_;
    uint4 r;
    r.x = f2h(row[inp[(b + 0) * V_ + v]], row[inp[(b + 1) * V_ + v]]);
    r.y = f2h(row[inp[(b + 2) * V_ + v]], row[inp[(b + 3) * V_ + v]]);
    r.z = f2h(row[inp[(b + 4) * V_ + v]], row[inp[(b + 5) * V_ + v]]);
    r.w = f2h(row[inp[(b + 6) * V_ + v]], row[inp[(b + 7) * V_ + v]]);
    *reinterpret_cast<uint4*>(nm + ((size_t)vk * B_ + b) / 2) = r;
}

// ---- product: em[e][bs] = sum_f nm[pc[e][f]][bs], batch-chunked per XCD ----
// block: 256 thr = 32 element-rows x 8 lanes; batch chunk = blockIdx & 7
__global__ __launch_bounds__(256, 4) void prod_k(
    const uint32_t* __restrict__ nm,  // [N,B] f16
    const int* __restrict__ pc,       // [E,PF]
    uint32_t* __restrict__ em)        // [E,B] f16
{
    const int bchunk = blockIdx.x & 7;
    const int e = (blockIdx.x >> 3) * 32 + (threadIdx.x >> 3);
    const int b = bchunk * BC + (threadIdx.x & 7) * 8;     // fp16 elem offset
    const int4 ch = *reinterpret_cast<const int4*>(pc + (size_t)e * 4);
    const size_t bo = (size_t)b / 2;                       // u32 offset within row
    const uint4 u0 = *reinterpret_cast<const uint4*>(nm + (size_t)ch.x * (B_ / 2) + bo);
    const uint4 u1 = *reinterpret_cast<const uint4*>(nm + (size_t)ch.y * (B_ / 2) + bo);
    const uint4 u2 = *reinterpret_cast<const uint4*>(nm + (size_t)ch.z * (B_ / 2) + bo);
    const uint4 u3 = *reinterpret_cast<const uint4*>(nm + (size_t)ch.w * (B_ / 2) + bo);
    uint4 r;
    {
        const float2 a0 = h2f(u0.x), a1 = h2f(u1.x), a2 = h2f(u2.x), a3 = h2f(u3.x);
        r.x = f2h((a0.x + a1.x) + (a2.x + a3.x), (a0.y + a1.y) + (a2.y + a3.y));
    }
    {
        const float2 a0 = h2f(u0.y), a1 = h2f(u1.y), a2 = h2f(u2.y), a3 = h2f(u3.y);
        r.y = f2h((a0.x + a1.x) + (a2.x + a3.x), (a0.y + a1.y) + (a2.y + a3.y));
    }
    {
        const float2 a0 = h2f(u0.z), a1 = h2f(u1.z), a2 = h2f(u2.z), a3 = h2f(u3.z);
        r.z = f2h((a0.x + a1.x) + (a2.x + a3.x), (a0.y + a1.y) + (a2.y + a3.y));
    }
    {
        const float2 a0 = h2f(u0.w), a1 = h2f(u1.w), a2 = h2f(u2.w), a3 = h2f(u3.w);
        r.w = f2h((a0.x + a1.x) + (a2.x + a3.x), (a0.y + a1.y) + (a2.y + a3.y));
    }
    *reinterpret_cast<uint4*>(em + (size_t)e * (B_ / 2) + bo) = r;
}

// ---- sum: nm[n][bs] = LSE_s( em[sc[n][s]][bs] + lw[n][s] ), batch-chunked ----
// online LSE over two halves of 8 children to cap register pressure
__global__ __launch_bounds__(256, 4) void sum_k(
    const uint32_t* __restrict__ em,   // [E,B] f16
    const int* __restrict__ sc,        // [N,SF]
    const float* __restrict__ lw,      // [N,SF]
    uint32_t* __restrict__ nm)         // [N,B] f16
{
    const int bchunk = blockIdx.x & 7;
    const int n = (blockIdx.x >> 3) * 32 + (threadIdx.x >> 3);
    const int b = bchunk * BC + (threadIdx.x & 7) * 8;
    const size_t bo = (size_t)b / 2;

    float m[8], acc[8];
    #pragma unroll
    for (int j = 0; j < 8; ++j) { m[j] = -3.0e38f; acc[j] = 0.f; }

    #pragma unroll
    for (int half = 0; half < 2; ++half) {
        const int s0 = half * 8;
        const int4 sa = *reinterpret_cast<const int4*>(sc + (size_t)n * SF_ + s0);
        const int4 sb = *reinterpret_cast<const int4*>(sc + (size_t)n * SF_ + s0 + 4);
        const float4 wa = *reinterpret_cast<const float4*>(lw + (size_t)n * SF_ + s0);
        const float4 wb = *reinterpret_cast<const float4*>(lw + (size_t)n * SF_ + s0 + 4);
        const int   si[8] = {sa.x, sa.y, sa.z, sa.w, sb.x, sb.y, sb.z, sb.w};
        const float wf[8] = {wa.x, wa.y, wa.z, wa.w, wb.x, wb.y, wb.z, wb.w};

        uint4 x[8];
        #pragma unroll
        for (int s = 0; s < 8; ++s)
            x[s] = *reinterpret_cast<const uint4*>(em + (size_t)si[s] * (B_ / 2) + bo);

        float cm[8];
        #pragma unroll
        for (int j = 0; j < 8; ++j) cm[j] = -3.0e38f;
        #pragma unroll
        for (int s = 0; s < 8; ++s) {
            const float w = wf[s];
            const float2 f0 = h2f(x[s].x), f1 = h2f(x[s].y);
            const float2 f2 = h2f(x[s].z), f3 = h2f(x[s].w);
            cm[0] = fmaxf(cm[0], f0.x + w); cm[1] = fmaxf(cm[1], f0.y + w);
            cm[2] = fmaxf(cm[2], f1.x + w); cm[3] = fmaxf(cm[3], f1.y + w);
            cm[4] = fmaxf(cm[4], f2.x + w); cm[5] = fmaxf(cm[5], f2.y + w);
            cm[6] = fmaxf(cm[6], f3.x + w); cm[7] = fmaxf(cm[7], f3.y + w);
        }
        // merge running state into new max
        #pragma unroll
        for (int j = 0; j < 8; ++j) {
            const float mm = fmaxf(m[j], cm[j]);
            acc[j] *= __expf(m[j] - mm);      // exp(-inf)=0 on first half
            m[j] = mm;
        }
        #pragma unroll
        for (int s = 0; s < 8; ++s) {
            const float w = wf[s];
            const float2 f0 = h2f(x[s].x), f1 = h2f(x[s].y);
            const float2 f2 = h2f(x[s].z), f3 = h2f(x[s].w);
            acc[0] += __expf(f0.x + w - m[0]); acc[1] += __expf(f0.y + w - m[1]);
            acc[2] += __expf(f1.x + w - m[2]); acc[3] += __expf(f1.y + w - m[3]);
            acc[4] += __expf(f2.x + w - m[4]); acc[5] += __expf(f2.y + w - m[5]);
            acc[6] += __expf(f3.x + w - m[6]); acc[7] += __expf(f3.y + w - m[7]);
        }
    }

    uint4 r;
    r.x = f2h(m[0] + __logf(acc[0]), m[1] + __logf(acc[1]));
    r.y = f2h(m[2] + __logf(acc[2]), m[3] + __logf(acc[3]));
    r.z = f2h(m[4] + __logf(acc[4]), m[5] + __logf(acc[5]));
    r.w = f2h(m[6] + __logf(acc[6]), m[7] + __logf(acc[7]));
    *reinterpret_cast<uint4*>(nm + (size_t)n * (B_ / 2) + bo) = r;
}

// ---- root stage 1: per-chunk online LSE over nodes ----
__global__ void root_part_k(const __half* __restrict__ nm,  // [N,B] f16
                            const float* __restrict__ rw,   // [N]
                            float* __restrict__ pm,         // [NCH,B]
                            float* __restrict__ ps)         // [NCH,B]
{
    const int b = blockIdx.x * blockDim.x + threadIdx.x;
    const int ch = blockIdx.y;
    const int n0 = ch * (N_ / NCH);
    float m = -3.0e38f, s = 0.f;
    for (int i = 0; i < N_ / NCH; ++i) {
        const int n = n0 + i;
        const float x = __half2float(nm[(size_t)n * B_ + b]) + rw[n];
        const float mn = fmaxf(m, x);
        s = s * __expf(m - mn) + __expf(x - mn);
        m = mn;
    }
    pm[ch * B_ + b] = m;
    ps[ch * B_ + b] = s;
}

// ---- root stage 2: combine ----
__global__ void root_comb_k(const float* __restrict__ pm,
                            const float* __restrict__ ps,
                            float* __restrict__ out)        // [B]
{
    const int b = blockIdx.x * blockDim.x + threadIdx.x;
    float m = -3.0e38f;
    for (int ch = 0; ch < NCH; ++ch) m = fmaxf(m, pm[ch * B_ + b]);
    float s = 0.f;
    for (int ch = 0; ch < NCH; ++ch) s += ps[ch * B_ + b] * __expf(pm[ch * B_ + b] - m);
    out[b] = m + __logf(s);
}

} // namespace

extern "C" void kernel_launch(void* const* d_in, const int* in_sizes, int n_in,
                              void* d_out, int out_size, void* d_ws, size_t ws_size,
                              hipStream_t stream) {
    const int*   inp = (const int*)d_in[0];     // [B,V]
    const float* lp  = (const float*)d_in[1];   // [V,K,C]
    const int*   pc  = (const int*)d_in[2];     // [L,E,PF]
    const int*   sc  = (const int*)d_in[3];     // [L,N,SF]
    const float* lw  = (const float*)d_in[4];   // [L,N,SF]
    const float* rw  = (const float*)d_in[5];   // [N]
    float*       out = (float*)d_out;           // [B,1]

    uint32_t* nm = (uint32_t*)d_ws;                      // 8 MB (f16)
    uint32_t* em = nm + (size_t)N_ * B_ / 2;             // 32 MB (f16)
    float*    pm = (float*)(em + (size_t)E_ * B_ / 2);
    float*    ps = pm + (size_t)NCH * B_;

    input_layer_k<<<(V_ * K_ * (B_ / 8)) / 256, 256, 0, stream>>>(inp, lp, nm);

    // prod: 32 rows/block, 8 batch chunks -> (E/32)*8 = 8192 blocks
    // sum:  32 rows/block, 8 batch chunks -> (N/32)*8 = 2048 blocks
    for (int l = 0; l < L_; ++l) {
        prod_k<<<(E_ / 32) * 8, 256, 0, stream>>>(nm, pc + (size_t)l * E_ * PF_, em);
        sum_k<<<(N_ / 32) * 8, 256, 0, stream>>>(
            em, sc + (size_t)l * N_ * SF_, lw + (size_t)l * N_ * SF_, nm);
    }

    root_part_k<<<dim3(B_ / 256, NCH), 256, 0, stream>>>((const __half*)nm, rw, pm, ps);
    root_comb_k<<<B_ / 256, 256, 0, stream>>>(pm, ps, out);
}